// Round 4
// baseline (63.958 us; speedup 1.0000x reference)
//
#include <hip/hip_runtime.h>

// NEmbedding: out[b,f,e] = relu( sum_n enc[b,f,n] * W[f,n,e] + bias[f,e] )
// enc[n] = (x - bins[n]) * g[n] for all n except the single containing bin k,
// where enc[k] = 1.  g[n] = 1/(hi[n]-lo[n]), hi[n] = bins[n+1] (or -1.0 at n=63).
// => out = relu( x*P[f,e] + R[f,e] + (1 - (x-bins[k])*g[k]) * W[f,k,e] )
//    P[f,e] = sum_n g[f,n] W[f,n,e];  R[f,e] = bias[f,e] - sum_n bins[f,n] g[f,n] W[f,n,e]
// k = largest n with bins[f,n] <= x (0 if none).
//
// R1: nontemporal output stores (don't thrash L2/L3 holding W); nt x loads.
// R2: ext_vector_type for nontemporal builtins.
// R3: (a) software-pipeline the W gather one 4-row group ahead so the
//     s_waitcnt consuming group q's loads never implies retirement of group
//     q-1's stores (vmcnt FIFO is in-order; loads must be issued BEFORE the
//     stores they'd otherwise queue behind). (b) drop the g[] table: stage a
//     -1.0 sentinel at sBins[f][64] and compute c = (hi-x)*rcp(hi-lo) purely
//     from LDS — removes 4 per-lane global gathers per thread.

#define FDIM 64
#define NB   64
#define EDIM 32
#define BT   16   // b-rows per block

typedef __attribute__((ext_vector_type(4))) float f32x4;

__global__ __launch_bounds__(64) void prep_kernel(
    const float* __restrict__ bins, const float* __restrict__ W,
    const float* __restrict__ bias,
    float* __restrict__ P, float* __restrict__ R)
{
    const int f = blockIdx.x;
    const int t = threadIdx.x;
    __shared__ float sg[NB];
    __shared__ float sb[NB];

    float lo = bins[f * NB + t];
    float hi = (t < NB - 1) ? bins[f * NB + t + 1] : -1.0f;
    float gv = 1.0f / (hi - lo);
    sg[t] = gv;
    sb[t] = lo;
    __syncthreads();

    if (t < EDIM) {
        float p = 0.0f, q = 0.0f;
        const float* Wf = W + (size_t)f * NB * EDIM + t;
        #pragma unroll
        for (int n = 0; n < NB; ++n) {
            float w = Wf[n * EDIM];
            p = fmaf(sg[n], w, p);
            q = fmaf(sb[n] * sg[n], w, q);
        }
        P[f * EDIM + t] = p;
        R[f * EDIM + t] = bias[f * EDIM + t] - q;
    }
}

__global__ __launch_bounds__(256) void nemb_kernel(
    const float* __restrict__ x, const float* __restrict__ bins,
    const float* __restrict__ W,
    const float* __restrict__ P, const float* __restrict__ R,
    float* __restrict__ out)
{
    // Padded bins rows (65): [0..63] = bins, [64] = -1.0 sentinel (the "hi"
    // of the last bin). Padding also de-conflicts the binary-search banks.
    __shared__ float sBins[FDIM * (NB + 1)];
    __shared__ float sX[BT * FDIM];
    __shared__ float sC[BT * FDIM];
    __shared__ int   sK[BT * FDIM];

    const int t  = threadIdx.x;
    const long b0 = (long)blockIdx.x * BT;

    // ---- Phase 1: stage bins + sentinel into padded LDS, stage x tile ----
    #pragma unroll
    for (int i = 0; i < 4; ++i) {
        int li = i * 256 + t;                 // float4 index
        f32x4 v = reinterpret_cast<const f32x4*>(bins)[li];
        int el = li * 4;
        int f = el >> 6, n = el & 63;         // n % 4 == 0, no row crossing
        float* d = &sBins[f * (NB + 1) + n];
        d[0] = v.x; d[1] = v.y; d[2] = v.z; d[3] = v.w;
    }
    if (t < FDIM) sBins[t * (NB + 1) + NB] = -1.0f;
    reinterpret_cast<f32x4*>(sX)[t] =
        __builtin_nontemporal_load(reinterpret_cast<const f32x4*>(x + b0 * FDIM) + t);

    // Hoist this thread's P/R fragments (fixed (f, e-quad) across all b rows).
    const int fA = t >> 3;            // pass 0: f in 0..31
    const int fB = 32 + (t >> 3);     // pass 1: f in 32..63
    const int e0 = (t & 7) * 4;
    const f32x4 PA = *reinterpret_cast<const f32x4*>(P + fA * EDIM + e0);
    const f32x4 RA = *reinterpret_cast<const f32x4*>(R + fA * EDIM + e0);
    const f32x4 PB = *reinterpret_cast<const f32x4*>(P + fB * EDIM + e0);
    const f32x4 RB = *reinterpret_cast<const f32x4*>(R + fB * EDIM + e0);

    __syncthreads();

    // ---- Phase 2: per-(b,f) binary search; write (k, c) to LDS ----
    {
        const int f2  = t & 63;
        const int bi0 = t >> 6;               // 0..3
        const float* bl = &sBins[f2 * (NB + 1)];
        #pragma unroll
        for (int i = 0; i < 4; ++i) {
            int bi = bi0 + 4 * i;             // covers 0..15
            float xv = sX[bi * FDIM + f2];
            int k = (bl[32] <= xv) ? 32 : 0;
            if (bl[k + 16] <= xv) k += 16;
            if (bl[k +  8] <= xv) k +=  8;
            if (bl[k +  4] <= xv) k +=  4;
            if (bl[k +  2] <= xv) k +=  2;
            if (bl[k +  1] <= xv) k +=  1;
            float lo = bl[k];
            float hi = bl[k + 1];             // k=63 -> sentinel -1.0
            float c  = (hi - xv) * __builtin_amdgcn_rcpf(hi - lo);
            sC[bi * FDIM + f2] = c;
            sK[bi * FDIM + f2] = k;
        }
    }
    __syncthreads();

    // ---- Phase 3: 4 groups of 4 b-rows, W gather pipelined 1 group ahead ----
    float* ob = out + b0 * (FDIM * EDIM);
    f32x4 wA[2][4], wB[2][4];

    #pragma unroll
    for (int j = 0; j < 4; ++j) {             // prologue: gather group 0
        int kA = sK[j * FDIM + fA];
        int kB = sK[j * FDIM + fB];
        wA[0][j] = *reinterpret_cast<const f32x4*>(W + ((fA * NB + kA) * EDIM) + e0);
        wB[0][j] = *reinterpret_cast<const f32x4*>(W + ((fB * NB + kB) * EDIM) + e0);
    }

    #pragma unroll
    for (int q = 0; q < 4; ++q) {
        const int cur = q & 1, nxt = cur ^ 1;
        if (q < 3) {                          // gather group q+1 BEFORE stores q
            #pragma unroll
            for (int j = 0; j < 4; ++j) {
                int bi = (q + 1) * 4 + j;
                int kA = sK[bi * FDIM + fA];
                int kB = sK[bi * FDIM + fB];
                wA[nxt][j] = *reinterpret_cast<const f32x4*>(W + ((fA * NB + kA) * EDIM) + e0);
                wB[nxt][j] = *reinterpret_cast<const f32x4*>(W + ((fB * NB + kB) * EDIM) + e0);
            }
        }
        #pragma unroll
        for (int j = 0; j < 4; ++j) {
            int bi = q * 4 + j;
            float xAv = sX[bi * FDIM + fA];
            float cAv = sC[bi * FDIM + fA];
            float xBv = sX[bi * FDIM + fB];
            float cBv = sC[bi * FDIM + fB];
            f32x4 oA, oB;
            oA.x = fmaxf(fmaf(cAv, wA[cur][j].x, fmaf(xAv, PA.x, RA.x)), 0.0f);
            oA.y = fmaxf(fmaf(cAv, wA[cur][j].y, fmaf(xAv, PA.y, RA.y)), 0.0f);
            oA.z = fmaxf(fmaf(cAv, wA[cur][j].z, fmaf(xAv, PA.z, RA.z)), 0.0f);
            oA.w = fmaxf(fmaf(cAv, wA[cur][j].w, fmaf(xAv, PA.w, RA.w)), 0.0f);
            oB.x = fmaxf(fmaf(cBv, wB[cur][j].x, fmaf(xBv, PB.x, RB.x)), 0.0f);
            oB.y = fmaxf(fmaf(cBv, wB[cur][j].y, fmaf(xBv, PB.y, RB.y)), 0.0f);
            oB.z = fmaxf(fmaf(cBv, wB[cur][j].z, fmaf(xBv, PB.z, RB.z)), 0.0f);
            oB.w = fmaxf(fmaf(cBv, wB[cur][j].w, fmaf(xBv, PB.w, RB.w)), 0.0f);

            f32x4* orow = reinterpret_cast<f32x4*>(ob + (long)bi * (FDIM * EDIM));
            __builtin_nontemporal_store(oA, orow + t);
            __builtin_nontemporal_store(oB, orow + 256 + t);
        }
    }
}

extern "C" void kernel_launch(void* const* d_in, const int* in_sizes, int n_in,
                              void* d_out, int out_size, void* d_ws, size_t ws_size,
                              hipStream_t stream) {
    const float* x    = (const float*)d_in[0];   // (B, F)
    const float* bins = (const float*)d_in[1];   // (F, NB) sorted rows
    const float* W    = (const float*)d_in[2];   // (F, NB, E)
    const float* bias = (const float*)d_in[3];   // (F, E)
    float* out = (float*)d_out;

    // workspace layout: P (F*E) | R (F*E)  -> 16 KB total
    float* P = (float*)d_ws;
    float* R = P + FDIM * EDIM;

    const int B = in_sizes[0] / FDIM;

    prep_kernel<<<FDIM, 64, 0, stream>>>(bins, W, bias, P, R);
    nemb_kernel<<<B / BT, 256, 0, stream>>>(x, bins, W, P, R, out);
}

// Round 5
// 61.615 us; speedup vs baseline: 1.0380x; 1.0380x over previous
//
#include <hip/hip_runtime.h>

// NEmbedding: out[b,f,e] = relu( sum_n enc[b,f,n] * W[f,n,e] + bias[f,e] )
// enc[n] = (x - bins[n]) * g[n] for all n except the single containing bin k,
// where enc[k] = 1.  g[n] = 1/(hi[n]-lo[n]), hi[n] = bins[n+1] (or -1.0 at n=63).
// => out = relu( x*P[f,e] + R[f,e] + (1 - (x-bins[k])*g[k]) * W[f,k,e] )
//    P[f,e] = sum_n g[f,n] W[f,n,e];  R[f,e] = bias[f,e] - sum_n bins[f,n] g[f,n] W[f,n,e]
// k = largest n with bins[f,n] <= x (0 if none).
//
// R1/R2: load-before-store batching in phase 3 (106 -> 64 us).
// R3: pipelined W gather + LDS sentinel for c: NEUTRAL -> vmcnt-FIFO theory dead.
// R4: A/B the other half of R2's bundled change: plain stores instead of
//     nontemporal (fillBufferAligned proves plain stores reach 6.9 TB/s; our
//     1KB/wave stores fully cover cache lines so no RFO; hot 512KB W should
//     survive LRU). Orthogonal: prep_kernel now uses all 256 threads
//     (split n-sum + LDS reduce) instead of 32 threads x 64 serial loads.

#define FDIM 64
#define NB   64
#define EDIM 32
#define BT   16   // b-rows per block

typedef __attribute__((ext_vector_type(4))) float f32x4;

__global__ __launch_bounds__(256) void prep_kernel(
    const float* __restrict__ bins, const float* __restrict__ W,
    const float* __restrict__ bias,
    float* __restrict__ P, float* __restrict__ R)
{
    const int f = blockIdx.x;
    const int t = threadIdx.x;
    __shared__ float sg[NB];
    __shared__ float sb[NB];
    __shared__ float redP[8][EDIM];
    __shared__ float redQ[8][EDIM];

    if (t < NB) {
        float lo = bins[f * NB + t];
        float hi = (t < NB - 1) ? bins[f * NB + t + 1] : -1.0f;
        sg[t] = 1.0f / (hi - lo);
        sb[t] = lo;
    }
    __syncthreads();

    const int e  = t & (EDIM - 1);
    const int ch = t >> 5;                    // 0..7, each owns 8 n's
    float p = 0.0f, q = 0.0f;
    const float* Wf = W + (size_t)f * NB * EDIM + e;
    #pragma unroll
    for (int i = 0; i < 8; ++i) {
        int n = ch * 8 + i;
        float w = Wf[n * EDIM];
        p = fmaf(sg[n], w, p);
        q = fmaf(sb[n] * sg[n], w, q);
    }
    redP[ch][e] = p;
    redQ[ch][e] = q;
    __syncthreads();

    if (t < EDIM) {
        float P_ = 0.0f, Q_ = 0.0f;
        #pragma unroll
        for (int c = 0; c < 8; ++c) { P_ += redP[c][t]; Q_ += redQ[c][t]; }
        P[f * EDIM + t] = P_;
        R[f * EDIM + t] = bias[f * EDIM + t] - Q_;
    }
}

__global__ __launch_bounds__(256) void nemb_kernel(
    const float* __restrict__ x, const float* __restrict__ bins,
    const float* __restrict__ W,
    const float* __restrict__ P, const float* __restrict__ R,
    float* __restrict__ out)
{
    // Padded bins rows (65): [0..63] = bins, [64] = -1.0 sentinel (the "hi"
    // of the last bin). Padding also de-conflicts the binary-search banks.
    __shared__ float sBins[FDIM * (NB + 1)];
    __shared__ float sX[BT * FDIM];
    __shared__ float sC[BT * FDIM];
    __shared__ int   sK[BT * FDIM];

    const int t  = threadIdx.x;
    const long b0 = (long)blockIdx.x * BT;

    // ---- Phase 1: stage bins + sentinel into padded LDS, stage x tile ----
    #pragma unroll
    for (int i = 0; i < 4; ++i) {
        int li = i * 256 + t;                 // float4 index
        f32x4 v = reinterpret_cast<const f32x4*>(bins)[li];
        int el = li * 4;
        int f = el >> 6, n = el & 63;         // n % 4 == 0, no row crossing
        float* d = &sBins[f * (NB + 1) + n];
        d[0] = v.x; d[1] = v.y; d[2] = v.z; d[3] = v.w;
    }
    if (t < FDIM) sBins[t * (NB + 1) + NB] = -1.0f;
    reinterpret_cast<f32x4*>(sX)[t] =
        __builtin_nontemporal_load(reinterpret_cast<const f32x4*>(x + b0 * FDIM) + t);

    // Hoist this thread's P/R fragments (fixed (f, e-quad) across all b rows).
    const int fA = t >> 3;            // pass 0: f in 0..31
    const int fB = 32 + (t >> 3);     // pass 1: f in 32..63
    const int e0 = (t & 7) * 4;
    const f32x4 PA = *reinterpret_cast<const f32x4*>(P + fA * EDIM + e0);
    const f32x4 RA = *reinterpret_cast<const f32x4*>(R + fA * EDIM + e0);
    const f32x4 PB = *reinterpret_cast<const f32x4*>(P + fB * EDIM + e0);
    const f32x4 RB = *reinterpret_cast<const f32x4*>(R + fB * EDIM + e0);

    __syncthreads();

    // ---- Phase 2: per-(b,f) binary search; write (k, c) to LDS ----
    {
        const int f2  = t & 63;
        const int bi0 = t >> 6;               // 0..3
        const float* bl = &sBins[f2 * (NB + 1)];
        #pragma unroll
        for (int i = 0; i < 4; ++i) {
            int bi = bi0 + 4 * i;             // covers 0..15
            float xv = sX[bi * FDIM + f2];
            int k = (bl[32] <= xv) ? 32 : 0;
            if (bl[k + 16] <= xv) k += 16;
            if (bl[k +  8] <= xv) k +=  8;
            if (bl[k +  4] <= xv) k +=  4;
            if (bl[k +  2] <= xv) k +=  2;
            if (bl[k +  1] <= xv) k +=  1;
            float lo = bl[k];
            float hi = bl[k + 1];             // k=63 -> sentinel -1.0
            float c  = (hi - xv) * __builtin_amdgcn_rcpf(hi - lo);
            sC[bi * FDIM + f2] = c;
            sK[bi * FDIM + f2] = k;
        }
    }
    __syncthreads();

    // ---- Phase 3: 4 groups of 4 b-rows, W gather pipelined 1 group ahead ----
    float* ob = out + b0 * (FDIM * EDIM);
    f32x4 wA[2][4], wB[2][4];

    #pragma unroll
    for (int j = 0; j < 4; ++j) {             // prologue: gather group 0
        int kA = sK[j * FDIM + fA];
        int kB = sK[j * FDIM + fB];
        wA[0][j] = *reinterpret_cast<const f32x4*>(W + ((fA * NB + kA) * EDIM) + e0);
        wB[0][j] = *reinterpret_cast<const f32x4*>(W + ((fB * NB + kB) * EDIM) + e0);
    }

    #pragma unroll
    for (int q = 0; q < 4; ++q) {
        const int cur = q & 1, nxt = cur ^ 1;
        if (q < 3) {                          // gather group q+1 BEFORE stores q
            #pragma unroll
            for (int j = 0; j < 4; ++j) {
                int bi = (q + 1) * 4 + j;
                int kA = sK[bi * FDIM + fA];
                int kB = sK[bi * FDIM + fB];
                wA[nxt][j] = *reinterpret_cast<const f32x4*>(W + ((fA * NB + kA) * EDIM) + e0);
                wB[nxt][j] = *reinterpret_cast<const f32x4*>(W + ((fB * NB + kB) * EDIM) + e0);
            }
        }
        #pragma unroll
        for (int j = 0; j < 4; ++j) {
            int bi = q * 4 + j;
            float xAv = sX[bi * FDIM + fA];
            float cAv = sC[bi * FDIM + fA];
            float xBv = sX[bi * FDIM + fB];
            float cBv = sC[bi * FDIM + fB];
            f32x4 oA, oB;
            oA.x = fmaxf(fmaf(cAv, wA[cur][j].x, fmaf(xAv, PA.x, RA.x)), 0.0f);
            oA.y = fmaxf(fmaf(cAv, wA[cur][j].y, fmaf(xAv, PA.y, RA.y)), 0.0f);
            oA.z = fmaxf(fmaf(cAv, wA[cur][j].z, fmaf(xAv, PA.z, RA.z)), 0.0f);
            oA.w = fmaxf(fmaf(cAv, wA[cur][j].w, fmaf(xAv, PA.w, RA.w)), 0.0f);
            oB.x = fmaxf(fmaf(cBv, wB[cur][j].x, fmaf(xBv, PB.x, RB.x)), 0.0f);
            oB.y = fmaxf(fmaf(cBv, wB[cur][j].y, fmaf(xBv, PB.y, RB.y)), 0.0f);
            oB.z = fmaxf(fmaf(cBv, wB[cur][j].z, fmaf(xBv, PB.z, RB.z)), 0.0f);
            oB.w = fmaxf(fmaf(cBv, wB[cur][j].w, fmaf(xBv, PB.w, RB.w)), 0.0f);

            f32x4* orow = reinterpret_cast<f32x4*>(ob + (long)bi * (FDIM * EDIM));
            orow[t]       = oA;               // plain stores (R4 A/B vs nt)
            orow[256 + t] = oB;
        }
    }
}

extern "C" void kernel_launch(void* const* d_in, const int* in_sizes, int n_in,
                              void* d_out, int out_size, void* d_ws, size_t ws_size,
                              hipStream_t stream) {
    const float* x    = (const float*)d_in[0];   // (B, F)
    const float* bins = (const float*)d_in[1];   // (F, NB) sorted rows
    const float* W    = (const float*)d_in[2];   // (F, NB, E)
    const float* bias = (const float*)d_in[3];   // (F, E)
    float* out = (float*)d_out;

    // workspace layout: P (F*E) | R (F*E)  -> 16 KB total
    float* P = (float*)d_ws;
    float* R = P + FDIM * EDIM;

    const int B = in_sizes[0] / FDIM;

    prep_kernel<<<FDIM, 256, 0, stream>>>(bins, W, bias, P, R);
    nemb_kernel<<<B / BT, 256, 0, stream>>>(x, bins, W, P, R, out);
}